// Round 13
// baseline (117.951 us; speedup 1.0000x reference)
//
#include <hip/hip_runtime.h>
#include <cmath>

// SSIM stability loss: 1 - mean(SSIM(x,y)), 11x11 Gaussian (sigma=1.5), zero SAME
// padding, fp32, 32 x 1 x 512 x 512.
//
// R27 = R26 (barrier-free per-wave tiles, one 512-thr block/CU, 8 forced-
// resident independent waves, 64-col strip + private dbuf LDS tile) +
// latency-structure attack:
//  (1) 2-row paired processing: 12 ds_read_b128 -> ONE wait -> two
//      independent H-convs + two V-outputs. Halves wait-points/row,
//      doubles ILP between waits.
//  (2) tree-split accumulators: H-conv chains 12 -> 6 deep (even/odd
//      partials), V-conv 11 -> 6. +8 packed adds per row-pair (~1%).
//
// Rationale: R26 proved TLP exhausted (8 forced independent waves/CU ==
// ~5 waves: both 43% VALUBusy, 42us). Accounting: per H-row ~1360 wall cyc
// vs ~290 VALU-issue cyc/wave; 2 waves/SIMD -> 43%. The wave waits ~2.6x
// its compute per row in a wait->compute cadence; serial FMA chains +
// one wait-point/row are the last un-attacked structure. R21 semi-refuted
// LDS-pressure (-34% reads/px -> neutral), so this targets cadence not BW.
// PRE-COMMIT: >= 40us clean => structural plateau, declare next round.
//
// Inner math = R19/R25 proven: unscaled sum/diff channels u=x+y, v=x-y +
// squares (2C1/2C2 algebra); 6 aligned ds_read_b128/row; parity-folded
// 12-tap weight vector; 11-deep circular history; fp64 atomic finish.
// Predict: dur 42 -> 34-38 (theory right) or 41-43 (plateau). VALUBusy
// 43 -> 50-56% if right. Tripwires: VGPR <= ~160, WRITE_SIZE 16B, absmax 0.

#define IMG   512
#define BROWS 64
#define NHROW (BROWS + 10)   // 74 H-rows per band
#define NCHUNK 7             // ceil(74/11)
#define CHR   11             // rows per LDS chunk (== history depth)
#define WQUADS 20            // float4 col-quads staged per row per wave (80 cols)
#define WUNITS 40            // v4f units per staged row per wave
#define NQ (CHR * WQUADS)    // 220 quads per chunk per wave
#define WAVE_LDS (2 * CHR * WUNITS)        // v4f units per wave (dbuf)
#define LDS_BYTES (8 * WAVE_LDS * 16)      // 112640
#define NBLOCKS 256
#define NPIX  8388608.0

typedef float v2f __attribute__((ext_vector_type(2)));
typedef float v4f __attribute__((ext_vector_type(4)));

struct GaussW { float w[11]; };

__global__ __launch_bounds__(512, 1)
void ssim_stream_kernel(const float* __restrict__ x, const float* __restrict__ y,
                        double* __restrict__ acc_ws, unsigned long long* __restrict__ ctr,
                        float* __restrict__ out, GaussW gw) {
    extern __shared__ v4f dsm[];        // [8 waves][2 bufs][CHR][WUNITS]
    __shared__ float wavesum[8];

    const int tid  = threadIdx.x;
    const int w    = tid >> 6;          // wave id 0..7, owns a 64-col strip
    const int lane = tid & 63;
    const int c0 = w * 64;              // strip base col (block covers all 512)
    const int r0 = blockIdx.x * BROWS;
    const size_t img_off = (size_t)blockIdx.y * (IMG * IMG);
    const float* __restrict__ xb = x + img_off;
    const float* __restrict__ yb = y + img_off;

    v4f (*wtile)[CHR][WUNITS] =
        reinterpret_cast<v4f (*)[CHR][WUNITS]>(dsm + (size_t)w * WAVE_LDS);

    // lane's output col = c0 + lane; taps at staged cols lane+3 .. lane+13
    // (stage base c0-8). Aligned 6 x b128 window starting at unit ub.
    const int ub = (lane + 3) >> 1;
    const int p  = (lane + 3) & 1;      // parity: tap k sits at window pos p+k

    // 12-tap per-lane weight vector: window pos m covers staged col 2*ub + m;
    // logical tap k = m - p, so wv2[m] = w[m-p] (0 outside [0,10]).
    v2f wv2[12];
    #pragma unroll
    for (int m = 0; m < 12; ++m) {
        float lo = (m <= 10) ? gw.w[m] : 0.f;       // p == 0
        float hi = (m >= 1) ? gw.w[m - 1] : 0.f;    // p == 1
        float wm = p ? hi : lo;
        wv2[m][0] = wm; wv2[m][1] = wm;
    }
    v2f wp[11];                          // vertical weights (parity-free)
    #pragma unroll
    for (int k = 0; k < 11; ++k) { wp[k][0] = gw.w[k]; wp[k][1] = gw.w[k]; }

    float4 sxr[4], syr[4];   // staged regs for next chunk (4 iters x 64 lanes >= 220)

    auto load_chunk = [&](int c) {
        #pragma unroll
        for (int it = 0; it < 4; ++it) {
            int idx = lane + it * 64;
            int row = idx / WQUADS;
            int q   = idx - row * WQUADS;
            int gr = r0 - 5 + c * CHR + row;       // global image row
            int gc = c0 - 8 + q * 4;               // global col of float4 (16B aligned)
            float4 vx = make_float4(0.f, 0.f, 0.f, 0.f);
            float4 vy = vx;
            if (idx < NQ && (unsigned)gr < IMG && (unsigned)gc < IMG) {
                const float* px = xb + (size_t)gr * IMG + gc;
                const float* py = yb + (size_t)gr * IMG + gc;
                vx = *(const float4*)px;
                vy = *(const float4*)py;
            }
            sxr[it] = vx; syr[it] = vy;
        }
    };
    // stage as u=x+y, v=x-y (unscaled; zero padding maps to zero: linear)
    auto store_chunk = [&](int b) {
        #pragma unroll
        for (int it = 0; it < 4; ++it) {
            int idx = lane + it * 64;
            if (idx < NQ) {
                int row = idx / WQUADS;
                int q   = idx - row * WQUADS;
                const float4 vx = sxr[it], vy = syr[it];
                wtile[b][row][q * 2]     = (v4f){vx.x + vy.x, vx.x - vy.x,
                                                 vx.y + vy.y, vx.y - vy.y};
                wtile[b][row][q * 2 + 1] = (v4f){vx.z + vy.z, vx.z - vy.z,
                                                 vx.w + vy.w, vx.w - vy.w};
            }
        }
    };

    v2f histL[11];     // (hu, hv)     -- linear channel H-conv results
    v2f histQ[11];     // (huu, hvv)   -- quadratic channel H-conv results
    float lsum = 0.f;
    const float C1x2 = 2e-4f, C2x2 = 1.8e-3f;   // 2*C1, 2*C2 (unscaled algebra)

    // H-conv with tree-split (even/odd tap) partial chains, depth 6
    auto hconv = [&](int s, const v4f (&w6)[6]) {
        v2f hLa = (v2f){0.f, 0.f}, hLb = (v2f){0.f, 0.f};
        v2f hQa = (v2f){0.f, 0.f}, hQb = (v2f){0.f, 0.f};
        #pragma unroll
        for (int m = 0; m < 12; ++m) {
            v2f t = (m & 1) ? w6[m >> 1].zw : w6[m >> 1].xy;
            v2f q = t * t;                                       // v_pk_mul_f32
            if (m & 1) {
                hLb = __builtin_elementwise_fma(wv2[m], t, hLb);
                hQb = __builtin_elementwise_fma(wv2[m], q, hQb);
            } else {
                hLa = __builtin_elementwise_fma(wv2[m], t, hLa);
                hQa = __builtin_elementwise_fma(wv2[m], q, hQa);
            }
        }
        histL[s] = hLa + hLb;
        histQ[s] = hQa + hQb;
    };
    // V-conv with split partial chains (depth 6+5) + SSIM term
    auto vout = [&](int s) {
        v2f aLa = (v2f){0.f, 0.f}, aLb = (v2f){0.f, 0.f};
        v2f aQa = (v2f){0.f, 0.f}, aQb = (v2f){0.f, 0.f};
        #pragma unroll
        for (int j = 0; j < 11; ++j) {
            const int sl = (s + 1 + j) % 11;   // static per (s,j)
            if (j & 1) {
                aLb = __builtin_elementwise_fma(wp[j], histL[sl], aLb);
                aQb = __builtin_elementwise_fma(wp[j], histQ[sl], aQb);
            } else {
                aLa = __builtin_elementwise_fma(wp[j], histL[sl], aLa);
                aQa = __builtin_elementwise_fma(wp[j], histQ[sl], aQa);
            }
        }
        v2f aL = aLa + aLb;
        v2f aQ = aQa + aQb;
        float a = aL[0] * aL[0], bq = aL[1] * aL[1];
        float dm = a - bq;             // = 4 mx my
        float sm = a + bq;             // = 2(mx^2 + my^2)
        float num = (dm + C1x2) * ((aQ[0] - aQ[1]) - dm + C2x2);
        float den = (sm + C1x2) * ((aQ[0] + aQ[1]) - sm + C2x2);
        lsum += num * __builtin_amdgcn_rcpf(den);
    };

    load_chunk(0);
    store_chunk(0);
    // no barrier: DS ops of one wave complete in order; compiler inserts the
    // lgkmcnt before the first dependent ds_read use.

    #pragma unroll 1
    for (int c = 0; c < NCHUNK; ++c) {      // 7 chunks x 11 rows = 77 >= 74
        const int b = c & 1;
        if (c < NCHUNK - 1) load_chunk(c + 1);  // global loads overlap chunk-c compute
        const int lim = NHROW - c * CHR;        // valid rows this chunk (11 or 8)

        // 2-row pairs: 12 reads -> one wait -> 2 independent H-convs ->
        // 2 independent V-outputs. Pairs (0,1)(2,3)...(8,9), then 10 single.
        #pragma unroll
        for (int s2 = 0; s2 < CHR - 1; s2 += 2) {   // s2 = 0,2,4,6,8
            const bool v0 = (s2 < lim);             // wave-uniform guards
            const bool v1 = (s2 + 1 < lim);
            v4f wA[6], wB[6];
            if (v0) {
                #pragma unroll
                for (int i = 0; i < 6; ++i) wA[i] = wtile[b][s2][ub + i];
            }
            if (v1) {
                #pragma unroll
                for (int i = 0; i < 6; ++i) wB[i] = wtile[b][s2 + 1][ub + i];
            }
            if (v0) hconv(s2, wA);
            if (v1) hconv(s2 + 1, wB);
            if (v0 && c > 0) vout(s2);
            if (v1 && c > 0) vout(s2 + 1);
        }
        // s = 10 (only exists when lim == 11)
        if (10 < lim) {
            v4f wA[6];
            #pragma unroll
            for (int i = 0; i < 6; ++i) wA[i] = wtile[b][10][ub + i];
            hconv(10, wA);
            vout(10);                    // first output row of the band (c==0 included)
        }

        // write next chunk into this wave's OTHER buffer -- no barrier needed,
        // reads of buffer b above are older DS ops of the same wave (in-order).
        if (c < NCHUNK - 1) store_chunk(b ^ 1);
    }

    // ---- reduction: wave shuffle -> LDS -> block partial -> fp64 atomic ----
    #pragma unroll
    for (int off = 32; off > 0; off >>= 1)
        lsum += __shfl_down(lsum, off, 64);
    if (lane == 0) wavesum[w] = lsum;
    __syncthreads();
    if (tid == 0) {
        float bs = 0.f;
        #pragma unroll
        for (int i = 0; i < 8; ++i) bs += wavesum[i];
        atomicAdd(acc_ws, (double)bs);
        __threadfence();
        unsigned long long old = atomicAdd(ctr, 1ull);
        if (old == (unsigned long long)(NBLOCKS - 1)) {
            __threadfence();
            double total = atomicAdd(acc_ws, 0.0);   // atomic RMW sees all prior adds
            out[0] = (float)(1.0 - total / NPIX);
        }
    }
}

extern "C" void kernel_launch(void* const* d_in, const int* in_sizes, int n_in,
                              void* d_out, int out_size, void* d_ws, size_t ws_size,
                              hipStream_t stream) {
    const float* x = (const float*)d_in[0];   // heatmap_clean
    const float* y = (const float*)d_in[1];   // heatmap_adv
    float* out = (float*)d_out;
    double* acc = (double*)d_ws;
    unsigned long long* ctr = (unsigned long long*)((char*)d_ws + 8);

    // allow > 64 KB dynamic LDS (host-side attribute, graph-capture safe)
    static bool attr_set = false;
    if (!attr_set) {
        hipFuncSetAttribute(reinterpret_cast<const void*>(ssim_stream_kernel),
                            hipFuncAttributeMaxDynamicSharedMemorySize, LDS_BYTES);
        attr_set = true;
    }

    // zero the 16B of accumulator+counter state (capture-safe async memset)
    hipMemsetAsync(d_ws, 0, 16, stream);

    GaussW gw;
    double g[11], s = 0.0;
    for (int i = 0; i < 11; ++i) { double d = i - 5; g[i] = exp(-(d * d) / 4.5); s += g[i]; }
    for (int i = 0; i < 11; ++i) gw.w[i] = (float)(g[i] / s);

    dim3 grid(IMG / BROWS, 32);   // (8, 32) = 256 blocks = 1/CU, 8 indep waves forced
    ssim_stream_kernel<<<grid, 512, LDS_BYTES, stream>>>(x, y, acc, ctr, out, gw);
}